// Round 14
// baseline (611.933 us; speedup 1.0000x reference)
//
#include <hip/hip_runtime.h>
#include <math.h>

typedef __bf16     bf16x8 __attribute__((ext_vector_type(8)));
typedef _Float16   f16x8  __attribute__((ext_vector_type(8)));
typedef float      f32x4  __attribute__((ext_vector_type(4)));
typedef unsigned short u16x8 __attribute__((ext_vector_type(8)));

#define DEVI __device__ __forceinline__
constexpr int B_TOK = 32768;
constexpr int MAXT  = 520;
constexpr int NBLK  = B_TOK / 128;   // 256 fusion blocks, 128 tokens each

DEVI unsigned short f2bf(float f){
  unsigned int u = __builtin_bit_cast(unsigned int, f);
  u += 0x7fffu + ((u >> 16) & 1u);
  return (unsigned short)(u >> 16);
}
DEVI float bf2f(unsigned short b){
  return __builtin_bit_cast(float, (unsigned int)b << 16);
}
// A&S 7.1.26 erf approx, |err|<=1.5e-7 (branch-free)
DEVI float gelu_fast(float x){
  float z = fabsf(x) * 0.70710678118654752f;
  float t = __builtin_amdgcn_rcpf(1.f + 0.3275911f * z);
  float p = t*(0.254829592f + t*(-0.284496736f + t*(1.421413741f + t*(-1.453152027f + t*1.061405429f))));
  float e = __expf(-z * z);
  float erfz = 1.f - p * e;
  float s = copysignf(erfz, x);
  return 0.5f * x * (1.f + s);
}
DEVI void load16_lds(const void* g, void* l){
  __builtin_amdgcn_global_load_lds(
      (const __attribute__((address_space(1))) unsigned int*)g,
      (__attribute__((address_space(3))) unsigned int*)l, 16, 0, 0);
}
DEVI float wredsum(float v){
#pragma unroll
  for (int off = 32; off > 0; off >>= 1) v += __shfl_xor(v, off, 64);
  return v;
}

// ---------------- weight prep ----------------
__global__ void transpose_cast_bf16_k(const float* __restrict__ src, unsigned short* __restrict__ dst,
                                      int R, int C){
  __shared__ float tile[32][33];
  size_t base = (size_t)blockIdx.z * R * C;
  int c0 = blockIdx.x * 32, r0 = blockIdx.y * 32;
  for (int i = threadIdx.y; i < 32; i += 8)
    tile[i][threadIdx.x] = src[base + (size_t)(r0 + i) * C + c0 + threadIdx.x];
  __syncthreads();
  for (int i = threadIdx.y; i < 32; i += 8)
    dst[base + (size_t)(c0 + i) * R + r0 + threadIdx.x] = f2bf(tile[threadIdx.x][i]);
}

__global__ void transpose_split_f16_k(const float* __restrict__ src, unsigned short* __restrict__ dh,
                                      unsigned short* __restrict__ dl, int R, int C){
  __shared__ float tile[32][33];
  int c0 = blockIdx.x * 32, r0 = blockIdx.y * 32;
  for (int i = threadIdx.y; i < 32; i += 8)
    tile[i][threadIdx.x] = src[(size_t)(r0 + i) * C + c0 + threadIdx.x];
  __syncthreads();
  for (int i = threadIdx.y; i < 32; i += 8){
    float f = tile[threadIdx.x][i];
    _Float16 h = (_Float16)f;
    _Float16 l = (_Float16)(f - (float)h);
    size_t o = (size_t)(c0 + i) * R + r0 + threadIdx.x;
    dh[o] = __builtin_bit_cast(unsigned short, h);
    dl[o] = __builtin_bit_cast(unsigned short, l);
  }
}

// ------------- MEGA fusion: GEMM(f16-split) + LN + GELU + gate, full-row tiles -------------
// tile M=128, N=512 (full row), K_STEP=32; 512 threads = 8 waves (rowg 2 x colw 4).
// LDS swizzle (32-col u16 tiles): col-oct ^= row&3. D-layout: row=oct*4+r, col=lm.
__global__ __launch_bounds__(512, 2) void fusion_mega_k(
    const float* __restrict__ vis, const float* __restrict__ lang, const float* __restrict__ state,
    const unsigned short* __restrict__ Wh, const unsigned short* __restrict__ Wl,
    const float* __restrict__ bias, const float* __restrict__ gf, const float* __restrict__ betaf,
    const float* __restrict__ Wg, unsigned short* __restrict__ Xbf, int* __restrict__ PK,
    int* __restrict__ BlockCnt, float* __restrict__ BlockProbs)
{
  __shared__ alignas(16) unsigned char LDS[98816];       // 80K tiles + 16.9K lgP
  unsigned short* AhS = (unsigned short*)LDS;            // [128][32] u16, 8K
  unsigned short* AlS = (unsigned short*)(LDS + 8192);
  unsigned short* BhS = (unsigned short*)(LDS + 16384);  // [512][32] u16, 32K
  unsigned short* BlS = (unsigned short*)(LDS + 49152);
  float*          part= (float*)(LDS + 81920);           // [128][4] float2 (LN partials)
  float*          lgP = (float*)(LDS + 81920);           // [128][33] f32 (logit partials)
  unsigned short* xT  = (unsigned short*)LDS;            // [64][512] u16 staging (epilogue)
  __shared__ float s_probs[8];
  __shared__ int   s_cnt[8];
  __shared__ int   s_pk[128];
  __shared__ float s_w[128];

  const int tid = threadIdx.x;
  const int lane = tid & 63;
  const int w = tid >> 6;
  const int rowg = w >> 2, colw = w & 3;
  const int lm = lane & 15;
  const int oct = lane >> 4;            // 0..3
  const int lk4 = oct * 4;
  if (tid < 8){ s_cnt[tid] = 0; s_probs[tid] = 0.f; }

  // staging constants
  const int arow_l = tid >> 2;                       // 0..127
  const size_t arow_g = (size_t)blockIdx.x * 128 + arow_l;
  const int acol8 = (tid & 3) * 8;
  const int adst  = arow_l * 32 + ((((acol8 >> 3) ^ (arow_l & 3))) << 3);
  const int brow0 = tid >> 2;                        // + rd*128
  const int bswz  = (((tid & 3) ^ ((tid >> 2) & 3)) << 3);

  f32x4 acc[4][8] = {};
  for (int k0 = 0; k0 < 512; k0 += 32){
    // B: full W^T tile via async gload_lds (pre-swizzled source)
#pragma unroll
    for (int rd = 0; rd < 4; ++rd){
      int row = rd * 128 + brow0;
      size_t so = (size_t)row * 512 + k0 + bswz;
      int d8 = (rd * 512 + tid) * 8;
      load16_lds(Wh + so, &BhS[d8]);
      load16_lds(Wl + so, &BlS[d8]);
    }
    // A: reg-staged concat + f16 split (32-aligned segment boundaries)
    {
      int k = k0 + acol8;
      const float* src;
      if (k < 256)      src = vis   + arow_g * 256 + k;
      else if (k < 384) src = lang  + arow_g * 128 + (k - 256);
      else              src = state + arow_g * 128 + (k - 384);
      float4 a0 = *(const float4*)src, a1 = *(const float4*)(src + 4);
      float f[8] = {a0.x, a0.y, a0.z, a0.w, a1.x, a1.y, a1.z, a1.w};
      u16x8 hh, ll;
#pragma unroll
      for (int j = 0; j < 8; ++j){
        _Float16 h = (_Float16)f[j];
        _Float16 l = (_Float16)(f[j] - (float)h);
        hh[j] = __builtin_bit_cast(unsigned short, h);
        ll[j] = __builtin_bit_cast(unsigned short, l);
      }
      *(u16x8*)&AhS[adst] = hh;
      *(u16x8*)&AlS[adst] = ll;
    }
    __syncthreads();
    f16x8 fah[4], fal[4];
#pragma unroll
    for (int m = 0; m < 4; ++m){
      int row = rowg * 64 + m * 16 + lm;
      int ro = row * 32 + ((oct ^ (lm & 3)) << 3);
      fah[m] = *(const f16x8*)&AhS[ro];
      fal[m] = *(const f16x8*)&AlS[ro];
    }
#pragma unroll
    for (int nh = 0; nh < 2; ++nh){
      f16x8 fbh[4], fbl[4];
#pragma unroll
      for (int nn = 0; nn < 4; ++nn){
        int nrow = colw * 128 + (nh * 4 + nn) * 16 + lm;
        int ro = nrow * 32 + ((oct ^ (lm & 3)) << 3);
        fbh[nn] = *(const f16x8*)&BhS[ro];
        fbl[nn] = *(const f16x8*)&BlS[ro];
      }
#pragma unroll
      for (int m = 0; m < 4; ++m)
#pragma unroll
        for (int nn = 0; nn < 4; ++nn){
          int n = nh * 4 + nn;
          acc[m][n] = __builtin_amdgcn_mfma_f32_16x16x32_f16(fah[m], fbh[nn], acc[m][n], 0, 0, 0);
          acc[m][n] = __builtin_amdgcn_mfma_f32_16x16x32_f16(fal[m], fbh[nn], acc[m][n], 0, 0, 0);
          acc[m][n] = __builtin_amdgcn_mfma_f32_16x16x32_f16(fah[m], fbl[nn], acc[m][n], 0, 0, 0);
        }
    }
    __syncthreads();
  }

  // ---- epilogue ----
  float bvn[8], gn[8], btn[8];
#pragma unroll
  for (int n = 0; n < 8; ++n){
    int c = colw * 128 + n * 16 + lm;
    bvn[n] = bias[c]; gn[n] = gf[c]; btn[n] = betaf[c];
  }
  // LN partials: per-lane 16 rows, sum over its 8 cols; reduce across lm; write [row][colw]
  float s1v[16], s2v[16];
#pragma unroll
  for (int m = 0; m < 4; ++m)
#pragma unroll
    for (int r = 0; r < 4; ++r){
      float s1 = 0.f, s2 = 0.f;
#pragma unroll
      for (int n = 0; n < 8; ++n){
        float v = acc[m][n][r] + bvn[n];
        s1 += v; s2 += v * v;
      }
      s1v[m*4+r] = s1; s2v[m*4+r] = s2;
    }
#pragma unroll
  for (int off = 1; off < 16; off <<= 1)
#pragma unroll
    for (int i = 0; i < 16; ++i){
      s1v[i] += __shfl_xor(s1v[i], off, 64);
      s2v[i] += __shfl_xor(s2v[i], off, 64);
    }
  if (lm == 0){
#pragma unroll
    for (int m = 0; m < 4; ++m)
#pragma unroll
      for (int r = 0; r < 4; ++r){
        int row = rowg * 64 + m * 16 + lk4 + r;
        part[(row * 4 + colw) * 2]     = s1v[m*4+r];
        part[(row * 4 + colw) * 2 + 1] = s2v[m*4+r];
      }
  }
  __syncthreads();
  float muv[16], invv[16];
#pragma unroll
  for (int m = 0; m < 4; ++m)
#pragma unroll
    for (int r = 0; r < 4; ++r){
      int row = rowg * 64 + m * 16 + lk4 + r;
      float s1 = part[row*8] + part[row*8+2] + part[row*8+4] + part[row*8+6];
      float s2 = part[row*8+1] + part[row*8+3] + part[row*8+5] + part[row*8+7];
      float mu = s1 * (1.f/512.f);
      float var = s2 * (1.f/512.f) - mu * mu;
      muv[m*4+r] = mu;
      invv[m*4+r] = 1.f / sqrtf(var + 1e-5f);
    }
  __syncthreads();   // part consumed; lgP may now overwrite
  // o in-place (f32): gelu(LN(x)*g+b)
#pragma unroll
  for (int m = 0; m < 4; ++m)
#pragma unroll
    for (int n = 0; n < 8; ++n)
#pragma unroll
      for (int r = 0; r < 4; ++r)
        acc[m][n][r] = gelu_fast((acc[m][n][r] + bvn[n] - muv[m*4+r]) * invv[m*4+r] * gn[n] + btn[n]);
  // gate weights for this lane's 8 cols
  float wgv[8][8];
#pragma unroll
  for (int n = 0; n < 8; ++n){
    int c = colw * 128 + n * 16 + lm;
    float4 w0 = *(const float4*)&Wg[(size_t)c * 8];
    float4 w1 = *(const float4*)&Wg[(size_t)c * 8 + 4];
    wgv[n][0]=w0.x; wgv[n][1]=w0.y; wgv[n][2]=w0.z; wgv[n][3]=w0.w;
    wgv[n][4]=w1.x; wgv[n][5]=w1.y; wgv[n][6]=w1.z; wgv[n][7]=w1.w;
  }
  // logit partials: per expert, fold cols then reduce across lm -> lgP[row][colw*8+e]
#pragma unroll
  for (int e = 0; e < 8; ++e){
    float p[16];
#pragma unroll
    for (int m = 0; m < 4; ++m)
#pragma unroll
      for (int r = 0; r < 4; ++r){
        float s = 0.f;
#pragma unroll
        for (int n = 0; n < 8; ++n) s += acc[m][n][r] * wgv[n][e];
        p[m*4+r] = s;
      }
#pragma unroll
    for (int off = 1; off < 16; off <<= 1)
#pragma unroll
      for (int i = 0; i < 16; ++i) p[i] += __shfl_xor(p[i], off, 64);
    if (lm == 0){
#pragma unroll
      for (int m = 0; m < 4; ++m)
#pragma unroll
        for (int r = 0; r < 4; ++r){
          int row = rowg * 64 + m * 16 + lk4 + r;
          lgP[row * 33 + colw * 8 + e] = p[m*4+r];
        }
    }
  }
  __syncthreads();
  // XBF: two row-group passes through swizzled LDS tile, coalesced flush
  // xT = [64][512] u16 = 4096 u16x8 groups -> 512 threads x 8 iterations
#pragma unroll
  for (int pp = 0; pp < 2; ++pp){
    if (rowg == pp){
#pragma unroll
      for (int m = 0; m < 4; ++m)
#pragma unroll
        for (int n = 0; n < 8; ++n)
#pragma unroll
          for (int r = 0; r < 4; ++r){
            int lr = m * 16 + lk4 + r;
            int col = colw * 128 + n * 16 + lm;
            xT[lr * 512 + (col ^ ((lr & 7) << 3))] = f2bf(acc[m][n][r]);
          }
    }
    __syncthreads();
#pragma unroll
    for (int rr = 0; rr < 8; ++rr){
      int idx = rr * 512 + tid;
      int row = idx >> 6, c8 = (idx & 63) * 8;
      u16x8 v = *(const u16x8*)&xT[row * 512 + (c8 ^ ((row & 7) << 3))];
      *(u16x8*)&Xbf[((size_t)blockIdx.x * 128 + pp * 64 + row) * 512 + c8] = v;
    }
    __syncthreads();
  }
  // token phase: 128 tokens, softmax/top-2/rank from lgP
  if (tid < 128){
    const int tk = tid;
    float lg[8];
#pragma unroll
    for (int e = 0; e < 8; ++e)
      lg[e] = lgP[tk*33 + e] + lgP[tk*33 + 8 + e] + lgP[tk*33 + 16 + e] + lgP[tk*33 + 24 + e];
    float mx = lg[0];
#pragma unroll
    for (int e = 1; e < 8; ++e) mx = fmaxf(mx, lg[e]);
    float pe[8], ps = 0.f;
#pragma unroll
    for (int e = 0; e < 8; ++e){ pe[e] = __expf(lg[e] - mx); ps += pe[e]; }
    float invp = 1.f / ps;
#pragma unroll
    for (int e = 0; e < 8; ++e) atomicAdd(&s_probs[e], pe[e] * invp);
    int i1 = 0;
#pragma unroll
    for (int e = 1; e < 8; ++e) if (lg[e] > lg[i1]) i1 = e;
    int i2 = (i1 == 0) ? 1 : 0;
#pragma unroll
    for (int e = 0; e < 8; ++e) if (e != i1 && lg[e] > lg[i2]) i2 = e;
    float wA = 1.f / (1.f + __expf(lg[i2] - lg[i1]));
    int r0 = atomicAdd(&s_cnt[i1], 1);
    int r1 = atomicAdd(&s_cnt[i2], 1);
    s_pk[tk] = i1 | (r0 << 3) | (i2 << 10) | (r1 << 13);
    s_w[tk]  = wA;
  }
  __syncthreads();
  if (tid < 8){
    BlockCnt[blockIdx.x * 8 + tid] = s_cnt[tid];
    BlockProbs[blockIdx.x * 8 + tid] = s_probs[tid];
  }
  if (tid < 128){
    int t = blockIdx.x * 128 + tid;
    PK[2*t]   = s_pk[tid];
    PK[2*t+1] = __builtin_bit_cast(int, s_w[tid]);
  }
}

// ------------- batched expert GEMM; XCD-grouped 1-D mapping -------------
template<int K, int N, int NT, bool GATHER, bool GELU_ACT, bool GLOBAL_ROW>
__global__ __launch_bounds__(256, 2) void egemm_k(
    const unsigned short* __restrict__ A, const int* __restrict__ rowlist,
    const int* __restrict__ cnt, const int* __restrict__ nTilesP,
    const int* __restrict__ tileE, const int* __restrict__ tileR0,
    int chunkBase, int chunkTiles, int tpg,
    const unsigned short* __restrict__ W, const float* __restrict__ bias,
    unsigned short* __restrict__ Cout)
{
  const int g = blockIdx.x & 7;
  const int j = blockIdx.x >> 3;
  const int tloc = g * tpg + j / NT;
  const int ntile = j % NT;
  if (tloc >= chunkTiles) return;
  const int t = chunkBase + tloc;
  if (t >= nTilesP[0]) return;
  const int e = tileE[t], r0 = tileR0[t];
  int rows = cnt[e] - r0; rows = rows > 128 ? 128 : rows;
  __shared__ alignas(16) unsigned short smem[16384];
  unsigned short* As = smem;
  unsigned short* Bs = smem + 8192;
  const int tid = threadIdx.x;
  const int row_s = tid >> 3, col_s = (tid & 7) * 8;
  const int swz = (row_s & 7) << 3;
  const unsigned short *pa[4], *pb[4];
#pragma unroll
  for (int i = 0; i < 4; ++i){
    int ir = i * 32 + row_s;
    size_t arow;
    if (GATHER){
      int rr = ir < rows ? ir : rows - 1;
      arow = (size_t)rowlist[(size_t)e * B_TOK + r0 + rr];
    } else {
      arow = (size_t)tloc * 128 + ir;
    }
    pa[i] = A + arow * K + (col_s ^ swz);
    pb[i] = W + (size_t)e * ((size_t)N * K) + (size_t)(ntile * 128 + ir) * K + (col_s ^ swz);
  }
  const int w = tid >> 6, lane = tid & 63;
  const int wr = (w >> 1) * 64, wc = (w & 1) * 64;
  const int lm = lane & 15, lk8 = (lane >> 4) * 8;
  const int fxor = (lm & 7) << 3;
  f32x4 acc[4][4] = {};
  for (int k0 = 0; k0 < K; k0 += 64){
#pragma unroll
    for (int i = 0; i < 4; ++i) load16_lds(pa[i] + k0, &As[i*2048 + tid*8]);
#pragma unroll
    for (int i = 0; i < 4; ++i) load16_lds(pb[i] + k0, &Bs[i*2048 + tid*8]);
    __syncthreads();
#pragma unroll
    for (int kk = 0; kk < 64; kk += 32){
      bf16x8 a[4], b[4];
#pragma unroll
      for (int m = 0; m < 4; ++m)
        a[m] = *(const bf16x8*)&As[(wr + m*16 + lm)*64 + ((kk + lk8) ^ fxor)];
#pragma unroll
      for (int n = 0; n < 4; ++n)
        b[n] = *(const bf16x8*)&Bs[(wc + n*16 + lm)*64 + ((kk + lk8) ^ fxor)];
#pragma unroll
      for (int m = 0; m < 4; ++m)
#pragma unroll
        for (int n = 0; n < 4; ++n)
          acc[m][n] = __builtin_amdgcn_mfma_f32_16x16x32_bf16(a[m], b[n], acc[m][n], 0, 0, 0);
    }
    __syncthreads();
  }
  unsigned short* Cs = smem;
  const int lk4 = (lane >> 4) * 4;
#pragma unroll
  for (int n = 0; n < 4; ++n){
    float bv = bias[(size_t)e * N + ntile * 128 + wc + n*16 + lm];
#pragma unroll
    for (int m = 0; m < 4; ++m)
#pragma unroll
      for (int r = 0; r < 4; ++r){
        float v = acc[m][n][r] + bv;
        if (GELU_ACT) v = gelu_fast(v);
        int rr = wr + m*16 + lk4 + r;
        Cs[rr * 128 + ((wc + n*16 + lm) ^ ((rr & 7) << 3))] = f2bf(v);
      }
  }
  __syncthreads();
  const size_t outTile = GLOBAL_ROW ? (size_t)t * 128 : (size_t)tloc * 128;
#pragma unroll
  for (int jj = 0; jj < 8; ++jj){
    int r = jj*16 + (tid >> 4), c = (tid & 15) * 8;
    if (r < rows){
      u16x8 v = *(const u16x8*)&Cs[r*128 + (c ^ ((r & 7) << 3))];
      *(u16x8*)&Cout[(outTile + r) * N + ntile*128 + c] = v;
    }
  }
}

// ------------- K2: parallel scan (256 blocks) + tile table + lb loss -------------
__global__ __launch_bounds__(256) void scan_k(
    const int* __restrict__ BlockCnt, const float* __restrict__ BlockProbs,
    int* __restrict__ BlockBase, int* __restrict__ CNT, int* __restrict__ nTiles,
    int* __restrict__ tileE, int* __restrict__ tileR0, int* __restrict__ rowBase,
    float* __restrict__ lbOut)
{
  __shared__ int sS[8][256];
  __shared__ float sF[8][256];
  __shared__ int sTileBase[9];
  const int tid = threadIdx.x;
  int loc[8];
#pragma unroll
  for (int e = 0; e < 8; ++e){
    loc[e] = BlockCnt[tid*8 + e];
    sS[e][tid] = loc[e];
    sF[e][tid] = BlockProbs[tid*8 + e];
  }
  __syncthreads();
  for (int off = 1; off < 256; off <<= 1){
    int add[8];
#pragma unroll
    for (int e = 0; e < 8; ++e) add[e] = (tid >= off) ? sS[e][tid - off] : 0;
    __syncthreads();
#pragma unroll
    for (int e = 0; e < 8; ++e) sS[e][tid] += add[e];
    __syncthreads();
  }
  for (int off = 128; off > 0; off >>= 1){
    if (tid < off)
#pragma unroll
      for (int e = 0; e < 8; ++e) sF[e][tid] += sF[e][tid + off];
    __syncthreads();
  }
#pragma unroll
  for (int e = 0; e < 8; ++e)
    BlockBase[tid*8 + e] = sS[e][tid] - loc[e];
  if (tid == 0){
    int t = 0;
    float acc = 0.f;
    for (int e = 0; e < 8; ++e){
      int c = sS[e][255]; c = c < 0 ? 0 : (c > B_TOK ? B_TOK : c);
      CNT[e] = c;
      sTileBase[e] = t;
      rowBase[e] = t * 128;
      t += (c + 127) >> 7;
      acc += ((float)c / (float)(B_TOK * 2)) * (sF[e][0] / (float)B_TOK);
    }
    sTileBase[8] = t;
    nTiles[0] = t;
    lbOut[0] = 8.f * acc;
  }
  __syncthreads();
  const int ntot = sTileBase[8];
  for (int i = tid; i < MAXT; i += 256){
    int e = 0;
#pragma unroll
    for (int k = 1; k <= 8; ++k) if (i >= sTileBase[k]) e = k;
    if (i < ntot){ tileE[i] = e; tileR0[i] = (i - sTileBase[e]) * 128; }
    else { tileE[i] = 0; tileR0[i] = 0; }
  }
}

// ------------- K3: place tokens into routing lists (streaming, no atomics) -------------
__global__ __launch_bounds__(256) void place_k(
    const int* __restrict__ PK, const int* __restrict__ BlockBase,
    int* __restrict__ rowlist, int* __restrict__ TS, float* __restrict__ TW)
{
  const int t = blockIdx.x * 256 + threadIdx.x;
  int pk = PK[2*t];
  float w0 = __builtin_bit_cast(float, PK[2*t+1]);
  int e0 = pk & 7, r0 = (pk >> 3) & 127;
  int e1 = (pk >> 10) & 7, r1 = (pk >> 13) & 127;
  int blk = t >> 7;
  int p0 = BlockBase[blk*8 + e0] + r0;
  int p1 = BlockBase[blk*8 + e1] + r1;
  rowlist[(size_t)e0 * B_TOK + p0] = t;
  rowlist[(size_t)e1 * B_TOK + p1] = t;
  TS[2*t]   = (e0 << 15) | p0;  TW[2*t]   = w0;
  TS[2*t+1] = (e1 << 15) | p1;  TW[2*t+1] = 1.f - w0;
}

// ------------- final combine -------------
__global__ __launch_bounds__(256) void combine_k(
    const unsigned short* __restrict__ Xbf, const unsigned short* __restrict__ H3F,
    const int* __restrict__ TS, const float* __restrict__ TW,
    const int* __restrict__ rowBase, const float* __restrict__ ge,
    const float* __restrict__ be, float* __restrict__ out)
{
  const int tok = blockIdx.x * 4 + (threadIdx.x >> 6);
  const int lane = threadIdx.x & 63;
  u16x8 xb = *(const u16x8*)(Xbf + (size_t)tok * 512 + lane * 8);
  float x[8];
#pragma unroll
  for (int j = 0; j < 8; ++j) x[j] = bf2f(xb[j]);
  float o[8] = {0.f,0.f,0.f,0.f,0.f,0.f,0.f,0.f};
#pragma unroll
  for (int kslot = 0; kslot < 2; ++kslot){
    int sl = TS[tok*2 + kslot];
    float wgt = TW[tok*2 + kslot];
    int e = sl >> 15, p = sl & 32767;
    size_t hrow = (size_t)(rowBase[e] + p);
    u16x8 hb = *(const u16x8*)(H3F + hrow * 512 + lane * 8);
    float s[8];
#pragma unroll
    for (int j = 0; j < 8; ++j) s[j] = x[j] + bf2f(hb[j]);
    float sm = 0.f;
#pragma unroll
    for (int j = 0; j < 8; ++j) sm += s[j];
    sm = wredsum(sm);
    float mu = sm * (1.f / 512.f);
    float q = 0.f;
#pragma unroll
    for (int j = 0; j < 8; ++j){ float d = s[j] - mu; q += d * d; }
    q = wredsum(q);
    float inv = 1.f / sqrtf(q * (1.f / 512.f) + 1e-5f);
    const float4* gp = (const float4*)(ge + (size_t)e * 512 + lane * 8);
    const float4* bp = (const float4*)(be + (size_t)e * 512 + lane * 8);
    float4 g0 = gp[0], g1 = gp[1], c0 = bp[0], c1 = bp[1];
    float gg[8] = {g0.x,g0.y,g0.z,g0.w,g1.x,g1.y,g1.z,g1.w};
    float bb[8] = {c0.x,c0.y,c0.z,c0.w,c1.x,c1.y,c1.z,c1.w};
#pragma unroll
    for (int j = 0; j < 8; ++j)
      o[j] += wgt * ((s[j]-mu)*inv*gg[j] + bb[j]);
  }
  float* op = out + (size_t)tok * 512 + lane * 8;
  *(float4*)op       = make_float4(o[0], o[1], o[2], o[3]);
  *(float4*)(op + 4) = make_float4(o[4], o[5], o[6], o[7]);
}

extern "C" void kernel_launch(void* const* d_in, const int* in_sizes, int n_in,
                              void* d_out, int out_size, void* d_ws, size_t ws_size,
                              hipStream_t stream)
{
  (void)in_sizes; (void)n_in; (void)out_size;
  const float* vis   = (const float*)d_in[0];
  const float* lang  = (const float*)d_in[1];
  const float* state = (const float*)d_in[2];
  const float* Wf    = (const float*)d_in[3];
  const float* bf    = (const float*)d_in[4];
  const float* gf    = (const float*)d_in[5];
  const float* betaf = (const float*)d_in[6];
  const float* Wg    = (const float*)d_in[7];
  const float* W1    = (const float*)d_in[8];
  const float* b1    = (const float*)d_in[9];
  const float* W2    = (const float*)d_in[10];
  const float* b2    = (const float*)d_in[11];
  const float* W3    = (const float*)d_in[12];
  const float* b3    = (const float*)d_in[13];
  const float* ge    = (const float*)d_in[14];
  const float* be    = (const float*)d_in[15];

  char* ws = (char*)d_ws;
  size_t off = 0;
  auto alloc = [&](size_t n){ size_t o = off; off += (n + 255) & ~(size_t)255; return o; };

  unsigned short* WFH  = (unsigned short*)(ws + alloc((size_t)512*512*2));
  unsigned short* WFL  = (unsigned short*)(ws + alloc((size_t)512*512*2));
  unsigned short* W1T  = (unsigned short*)(ws + alloc((size_t)8*1024*512*2));
  unsigned short* W2T  = (unsigned short*)(ws + alloc((size_t)8*512*1024*2));
  unsigned short* W3T  = (unsigned short*)(ws + alloc((size_t)8*512*512*2));
  unsigned short* XBF  = (unsigned short*)(ws + alloc((size_t)B_TOK*512*2));
  int*            RLIST= (int*)(ws + alloc((size_t)8*B_TOK*4));
  int*            TS   = (int*)(ws + alloc((size_t)B_TOK*2*4));
  float*          TW   = (float*)(ws + alloc((size_t)B_TOK*2*4));
  int*            PK   = (int*)(ws + alloc((size_t)B_TOK*2*4));
  int*            BCNT = (int*)(ws + alloc((size_t)NBLK*8*4));
  float*          BPROB= (float*)(ws + alloc((size_t)NBLK*8*4));
  int*            BBASE= (int*)(ws + alloc((size_t)NBLK*8*4));
  int*            CNT  = (int*)(ws + alloc(64));
  int*            NT_  = (int*)(ws + alloc(64));
  int*            RB   = (int*)(ws + alloc(64));
  int*            TE   = (int*)(ws + alloc(MAXT*4));
  int*            TR   = (int*)(ws + alloc(MAXT*4));
  unsigned short* H3F  = (unsigned short*)(ws + alloc((size_t)MAXT*128*512*2));  // 68 MB persistent

  const size_t perTile = (size_t)128*1024*2 + (size_t)128*512*2;
  size_t remain = (ws_size > off) ? (ws_size - off) : 0;
  const int tch = (remain >= (size_t)260 * perTile) ? 260 : 130;
  const int nch = (tch == 260) ? 2 : 4;
  size_t regB = alloc((size_t)tch * perTile);
  unsigned short* H1   = (unsigned short*)(ws + regB);
  unsigned short* H2   = H1 + (size_t)tch*128*1024;
  const int tpg = (tch + 7) / 8;

  transpose_split_f16_k<<<dim3(16,16,1), dim3(32,8), 0, stream>>>(Wf, WFH, WFL, 512, 512);
  transpose_cast_bf16_k<<<dim3(32,16,8), dim3(32,8), 0, stream>>>(W1, W1T, 512, 1024);
  transpose_cast_bf16_k<<<dim3(16,32,8), dim3(32,8), 0, stream>>>(W2, W2T, 1024, 512);
  transpose_cast_bf16_k<<<dim3(16,16,8), dim3(32,8), 0, stream>>>(W3, W3T, 512, 512);
  fusion_mega_k<<<NBLK, 512, 0, stream>>>(vis, lang, state, WFH, WFL, bf, gf, betaf, Wg,
                                          XBF, PK, BCNT, BPROB);
  scan_k<<<1, 256, 0, stream>>>(BCNT, BPROB, BBASE, CNT, NT_, TE, TR, RB,
                                ((float*)d_out) + (size_t)B_TOK*512);
  place_k<<<B_TOK/256, 256, 0, stream>>>(PK, BBASE, RLIST, TS, TW);

  for (int c = 0; c < nch; ++c){
    int cb = c * tch;
    egemm_k<512, 1024, 8, true,  true,  false><<<dim3(8*tpg*8), 256, 0, stream>>>(
        XBF, RLIST, CNT, NT_, TE, TR, cb, tch, tpg, W1T, b1, H1);
    egemm_k<1024, 512, 4, false, true,  false><<<dim3(8*tpg*4), 256, 0, stream>>>(
        H1,  RLIST, CNT, NT_, TE, TR, cb, tch, tpg, W2T, b2, H2);
    egemm_k<512,  512, 4, false, false, true ><<<dim3(8*tpg*4), 256, 0, stream>>>(
        H2,  RLIST, CNT, NT_, TE, TR, cb, tch, tpg, W3T, b3, H3F);
  }
  combine_k<<<B_TOK/4, 256, 0, stream>>>(XBF, H3F, TS, TW, RB, ge, be, (float*)d_out);
}

// Round 15
// 463.579 us; speedup vs baseline: 1.3200x; 1.3200x over previous
//
#include <hip/hip_runtime.h>
#include <math.h>

typedef __bf16     bf16x8 __attribute__((ext_vector_type(8)));
typedef _Float16   f16x8  __attribute__((ext_vector_type(8)));
typedef float      f32x4  __attribute__((ext_vector_type(4)));
typedef unsigned short u16x8 __attribute__((ext_vector_type(8)));

#define DEVI __device__ __forceinline__
constexpr int B_TOK = 32768;
constexpr int MAXT  = 520;
constexpr int NBLK  = B_TOK / 16;   // gate blocks (16 tokens each)

DEVI unsigned short f2bf(float f){
  unsigned int u = __builtin_bit_cast(unsigned int, f);
  u += 0x7fffu + ((u >> 16) & 1u);
  return (unsigned short)(u >> 16);
}
DEVI float bf2f(unsigned short b){
  return __builtin_bit_cast(float, (unsigned int)b << 16);
}
// A&S 7.1.26 erf approx, |err|<=1.5e-7 (branch-free)
DEVI float gelu_fast(float x){
  float z = fabsf(x) * 0.70710678118654752f;
  float t = __builtin_amdgcn_rcpf(1.f + 0.3275911f * z);
  float p = t*(0.254829592f + t*(-0.284496736f + t*(1.421413741f + t*(-1.453152027f + t*1.061405429f))));
  float e = __expf(-z * z);
  float erfz = 1.f - p * e;
  float s = copysignf(erfz, x);
  return 0.5f * x * (1.f + s);
}
DEVI void load16_lds(const void* g, void* l){
  __builtin_amdgcn_global_load_lds(
      (const __attribute__((address_space(1))) unsigned int*)g,
      (__attribute__((address_space(3))) unsigned int*)l, 16, 0, 0);
}
DEVI float wredsum(float v){
#pragma unroll
  for (int off = 32; off > 0; off >>= 1) v += __shfl_xor(v, off, 64);
  return v;
}

// ---------------- weight prep ----------------
__global__ void transpose_cast_bf16_k(const float* __restrict__ src, unsigned short* __restrict__ dst,
                                      int R, int C){
  __shared__ float tile[32][33];
  size_t base = (size_t)blockIdx.z * R * C;
  int c0 = blockIdx.x * 32, r0 = blockIdx.y * 32;
  for (int i = threadIdx.y; i < 32; i += 8)
    tile[i][threadIdx.x] = src[base + (size_t)(r0 + i) * C + c0 + threadIdx.x];
  __syncthreads();
  for (int i = threadIdx.y; i < 32; i += 8)
    dst[base + (size_t)(c0 + i) * R + r0 + threadIdx.x] = f2bf(tile[threadIdx.x][i]);
}

__global__ void transpose_split_f16_k(const float* __restrict__ src, unsigned short* __restrict__ dh,
                                      unsigned short* __restrict__ dl, int R, int C){
  __shared__ float tile[32][33];
  int c0 = blockIdx.x * 32, r0 = blockIdx.y * 32;
  for (int i = threadIdx.y; i < 32; i += 8)
    tile[i][threadIdx.x] = src[(size_t)(r0 + i) * C + c0 + threadIdx.x];
  __syncthreads();
  for (int i = threadIdx.y; i < 32; i += 8){
    float f = tile[threadIdx.x][i];
    _Float16 h = (_Float16)f;
    _Float16 l = (_Float16)(f - (float)h);
    size_t o = (size_t)(c0 + i) * R + r0 + threadIdx.x;
    dh[o] = __builtin_bit_cast(unsigned short, h);
    dl[o] = __builtin_bit_cast(unsigned short, l);
  }
}

// ------------- fusion GEMM, fp16 split; A = concat(vis,lang,state) reg-staged -------------
__global__ __launch_bounds__(256, 2) void gemm_fusion_f16split(
    const float* __restrict__ vis, const float* __restrict__ lang, const float* __restrict__ state,
    const unsigned short* __restrict__ Wh, const unsigned short* __restrict__ Wl,
    const float* __restrict__ bias, float* __restrict__ Xpre)
{
  constexpr int K = 512, N = 512;
  __shared__ alignas(16) unsigned short smemF[32768];   // 64 KB
  unsigned short* AhS = smemF;
  unsigned short* AlS = smemF + 8192;
  unsigned short* BhS = smemF + 16384;
  unsigned short* BlS = smemF + 24576;
  const int tid = threadIdx.x;
  const int row_s = tid >> 3, col_s = (tid & 7) * 8;
  const int swz = (row_s & 7) << 3;
  const unsigned short *pbh[4], *pbl[4];
  int arow[4];
#pragma unroll
  for (int i = 0; i < 4; ++i){
    arow[i] = blockIdx.x * 128 + i * 32 + row_s;
    size_t br = (size_t)(blockIdx.y * 128 + i * 32 + row_s) * K + (col_s ^ swz);
    pbh[i] = Wh + br; pbl[i] = Wl + br;
  }
  const int w = tid >> 6, lane = tid & 63;
  const int wr = (w >> 1) * 64, wc = (w & 1) * 64;
  const int lm = lane & 15, lk8 = (lane >> 4) * 8;
  const int fxor = (lm & 7) << 3;
  f32x4 acc[4][4] = {};
  for (int k0 = 0; k0 < K; k0 += 64){
#pragma unroll
    for (int i = 0; i < 4; ++i){
      load16_lds(pbh[i] + k0, &BhS[i*2048 + tid*8]);
      load16_lds(pbl[i] + k0, &BlS[i*2048 + tid*8]);
    }
    int col = k0 + col_s;
#pragma unroll
    for (int i = 0; i < 4; ++i){
      const float* src;
      if (col < 256)      src = vis   + (size_t)arow[i] * 256 + col;
      else if (col < 384) src = lang  + (size_t)arow[i] * 128 + (col - 256);
      else                src = state + (size_t)arow[i] * 128 + (col - 384);
      float4 a = *(const float4*)src, b = *(const float4*)(src + 4);
      float f[8] = {a.x, a.y, a.z, a.w, b.x, b.y, b.z, b.w};
      u16x8 hh, ll;
#pragma unroll
      for (int j = 0; j < 8; ++j){
        _Float16 h = (_Float16)f[j];
        _Float16 l = (_Float16)(f[j] - (float)h);
        hh[j] = __builtin_bit_cast(unsigned short, h);
        ll[j] = __builtin_bit_cast(unsigned short, l);
      }
      *(u16x8*)&AhS[i*2048 + row_s*64 + (col_s ^ swz)] = hh;
      *(u16x8*)&AlS[i*2048 + row_s*64 + (col_s ^ swz)] = ll;
    }
    __syncthreads();
#pragma unroll
    for (int kk = 0; kk < 64; kk += 32){
      f16x8 fah[4], fal[4], fbh[4], fbl[4];
#pragma unroll
      for (int m = 0; m < 4; ++m){
        int ro = (wr + m*16 + lm) * 64 + ((kk + lk8) ^ fxor);
        fah[m] = *(const f16x8*)&AhS[ro];
        fal[m] = *(const f16x8*)&AlS[ro];
      }
#pragma unroll
      for (int n = 0; n < 4; ++n){
        int ro = (wc + n*16 + lm) * 64 + ((kk + lk8) ^ fxor);
        fbh[n] = *(const f16x8*)&BhS[ro];
        fbl[n] = *(const f16x8*)&BlS[ro];
      }
#pragma unroll
      for (int m = 0; m < 4; ++m)
#pragma unroll
        for (int n = 0; n < 4; ++n){
          acc[m][n] = __builtin_amdgcn_mfma_f32_16x16x32_f16(fah[m], fbh[n], acc[m][n], 0, 0, 0);
          acc[m][n] = __builtin_amdgcn_mfma_f32_16x16x32_f16(fal[m], fbh[n], acc[m][n], 0, 0, 0);
          acc[m][n] = __builtin_amdgcn_mfma_f32_16x16x32_f16(fah[m], fbl[n], acc[m][n], 0, 0, 0);
        }
    }
    __syncthreads();
  }
  float* Cs = (float*)smemF;
  const int lk4 = (lane >> 4) * 4;
#pragma unroll
  for (int n = 0; n < 4; ++n){
    float bv = bias[blockIdx.y * 128 + wc + n*16 + lm];
#pragma unroll
    for (int m = 0; m < 4; ++m)
#pragma unroll
      for (int r = 0; r < 4; ++r){
        int rr = wr + m*16 + lk4 + r;
        Cs[rr * 128 + ((wc + n*16 + lm) ^ ((rr & 7) << 2))] = acc[m][n][r] + bv;
      }
  }
  __syncthreads();
#pragma unroll
  for (int j = 0; j < 16; ++j){
    int r = j*8 + (tid >> 5), c = (tid & 31) * 4;
    float4 v = *(const float4*)&Cs[r*128 + (c ^ ((r & 7) << 2))];
    *(float4*)&Xpre[(size_t)(blockIdx.x*128 + r) * N + blockIdx.y*128 + c] = v;
  }
}

// ------------- batched expert GEMM; XCD-grouped 1-D mapping -------------
template<int K, int N, int NT, bool GATHER, bool GELU_ACT, bool GLOBAL_ROW>
__global__ __launch_bounds__(256, 2) void egemm_k(
    const unsigned short* __restrict__ A, const int* __restrict__ rowlist,
    const int* __restrict__ cnt, const int* __restrict__ nTilesP,
    const int* __restrict__ tileE, const int* __restrict__ tileR0,
    int chunkBase, int chunkTiles, int tpg,
    const unsigned short* __restrict__ W, const float* __restrict__ bias,
    unsigned short* __restrict__ Cout)
{
  const int g = blockIdx.x & 7;
  const int j = blockIdx.x >> 3;
  const int tloc = g * tpg + j / NT;
  const int ntile = j % NT;
  if (tloc >= chunkTiles) return;
  const int t = chunkBase + tloc;
  if (t >= nTilesP[0]) return;
  const int e = tileE[t], r0 = tileR0[t];
  int rows = cnt[e] - r0; rows = rows > 128 ? 128 : rows;
  __shared__ alignas(16) unsigned short smem[16384];
  unsigned short* As = smem;
  unsigned short* Bs = smem + 8192;
  const int tid = threadIdx.x;
  const int row_s = tid >> 3, col_s = (tid & 7) * 8;
  const int swz = (row_s & 7) << 3;
  const unsigned short *pa[4], *pb[4];
#pragma unroll
  for (int i = 0; i < 4; ++i){
    int ir = i * 32 + row_s;
    size_t arow;
    if (GATHER){
      int rr = ir < rows ? ir : rows - 1;
      arow = (size_t)rowlist[(size_t)e * B_TOK + r0 + rr];
    } else {
      arow = (size_t)tloc * 128 + ir;
    }
    pa[i] = A + arow * K + (col_s ^ swz);
    pb[i] = W + (size_t)e * ((size_t)N * K) + (size_t)(ntile * 128 + ir) * K + (col_s ^ swz);
  }
  const int w = tid >> 6, lane = tid & 63;
  const int wr = (w >> 1) * 64, wc = (w & 1) * 64;
  const int lm = lane & 15, lk8 = (lane >> 4) * 8;
  const int fxor = (lm & 7) << 3;
  f32x4 acc[4][4] = {};
  for (int k0 = 0; k0 < K; k0 += 64){
#pragma unroll
    for (int i = 0; i < 4; ++i) load16_lds(pa[i] + k0, &As[i*2048 + tid*8]);
#pragma unroll
    for (int i = 0; i < 4; ++i) load16_lds(pb[i] + k0, &Bs[i*2048 + tid*8]);
    __syncthreads();
#pragma unroll
    for (int kk = 0; kk < 64; kk += 32){
      bf16x8 a[4], b[4];
#pragma unroll
      for (int m = 0; m < 4; ++m)
        a[m] = *(const bf16x8*)&As[(wr + m*16 + lm)*64 + ((kk + lk8) ^ fxor)];
#pragma unroll
      for (int n = 0; n < 4; ++n)
        b[n] = *(const bf16x8*)&Bs[(wc + n*16 + lm)*64 + ((kk + lk8) ^ fxor)];
#pragma unroll
      for (int m = 0; m < 4; ++m)
#pragma unroll
        for (int n = 0; n < 4; ++n)
          acc[m][n] = __builtin_amdgcn_mfma_f32_16x16x32_bf16(a[m], b[n], acc[m][n], 0, 0, 0);
    }
    __syncthreads();
  }
  unsigned short* Cs = smem;
  const int lk4 = (lane >> 4) * 4;
#pragma unroll
  for (int n = 0; n < 4; ++n){
    float bv = bias[(size_t)e * N + ntile * 128 + wc + n*16 + lm];
#pragma unroll
    for (int m = 0; m < 4; ++m)
#pragma unroll
      for (int r = 0; r < 4; ++r){
        float v = acc[m][n][r] + bv;
        if (GELU_ACT) v = gelu_fast(v);
        int rr = wr + m*16 + lk4 + r;
        Cs[rr * 128 + ((wc + n*16 + lm) ^ ((rr & 7) << 3))] = f2bf(v);
      }
  }
  __syncthreads();
  const size_t outTile = GLOBAL_ROW ? (size_t)t * 128 : (size_t)tloc * 128;
#pragma unroll
  for (int jj = 0; jj < 8; ++jj){
    int r = jj*16 + (tid >> 4), c = (tid & 15) * 8;
    if (r < rows){
      u16x8 v = *(const u16x8*)&Cs[r*128 + (c ^ ((r & 7) << 3))];
      *(u16x8*)&Cout[(outTile + r) * N + ntile*128 + c] = v;
    }
  }
}

// ------------- K1: LN + GELU + gate; NO global atomics (block-local records) -------------
__global__ __launch_bounds__(256) void ln_gelu_gate_k(
    const float* __restrict__ Xpre, const float* __restrict__ gf,
    const float* __restrict__ betaf, const float* __restrict__ Wg,
    unsigned short* __restrict__ Xbf, int* __restrict__ PK,
    int* __restrict__ BlockCnt, float* __restrict__ BlockProbs)
{
  __shared__ float s_probs[8];
  __shared__ int s_cnt[8];
  __shared__ int s_pk[16];
  __shared__ float s_w[16];
  const int tid = threadIdx.x, wv = tid >> 6, lane = tid & 63;
  if (tid < 8){ s_probs[tid] = 0.f; s_cnt[tid] = 0; }
  __syncthreads();
  float gg[8], bb[8], wg[8][8];
  {
    const float4* gp = (const float4*)(gf + lane * 8);
    const float4* bp = (const float4*)(betaf + lane * 8);
    float4 g0 = gp[0], g1 = gp[1], c0 = bp[0], c1 = bp[1];
    gg[0]=g0.x; gg[1]=g0.y; gg[2]=g0.z; gg[3]=g0.w; gg[4]=g1.x; gg[5]=g1.y; gg[6]=g1.z; gg[7]=g1.w;
    bb[0]=c0.x; bb[1]=c0.y; bb[2]=c0.z; bb[3]=c0.w; bb[4]=c1.x; bb[5]=c1.y; bb[6]=c1.z; bb[7]=c1.w;
#pragma unroll
    for (int j = 0; j < 8; ++j){
      const float4* wrow = (const float4*)(Wg + (size_t)(lane * 8 + j) * 8);
      float4 w0 = wrow[0], w1 = wrow[1];
      wg[j][0]=w0.x; wg[j][1]=w0.y; wg[j][2]=w0.z; wg[j][3]=w0.w;
      wg[j][4]=w1.x; wg[j][5]=w1.y; wg[j][6]=w1.z; wg[j][7]=w1.w;
    }
  }
  float4 vv[4][2];
#pragma unroll
  for (int it = 0; it < 4; ++it){
    const int row = blockIdx.x * 16 + wv * 4 + it;
    const float* xp = Xpre + (size_t)row * 512 + lane * 8;
    vv[it][0] = *(const float4*)xp;
    vv[it][1] = *(const float4*)(xp + 4);
  }
#pragma unroll
  for (int it = 0; it < 4; ++it){
    const int tloc = wv * 4 + it;
    const int row = blockIdx.x * 16 + tloc;
    float v[8] = {vv[it][0].x, vv[it][0].y, vv[it][0].z, vv[it][0].w,
                  vv[it][1].x, vv[it][1].y, vv[it][1].z, vv[it][1].w};
    float s1 = 0.f, s2 = 0.f;
#pragma unroll
    for (int j = 0; j < 8; ++j){ s1 += v[j]; s2 += v[j]*v[j]; }
    {
      float sel = (lane & 1) ? s1 : s2;
      float r = __shfl_xor(sel, 1, 64);
      float tt = ((lane & 1) ? s2 : s1) + r;
#pragma unroll
      for (int off = 2; off < 64; off <<= 1) tt += __shfl_xor(tt, off, 64);
      float other = __shfl_xor(tt, 1, 64);
      s1 = (lane & 1) ? other : tt;
      s2 = (lane & 1) ? tt : other;
    }
    const float mu  = s1 * (1.f / 512.f);
    const float var = s2 * (1.f / 512.f) - mu * mu;
    const float inv = 1.f / sqrtf(var + 1e-5f);
    float o[8];
#pragma unroll
    for (int j = 0; j < 8; ++j)
      o[j] = gelu_fast((v[j] - mu) * inv * gg[j] + bb[j]);
    u16x8 ob;
#pragma unroll
    for (int j = 0; j < 8; ++j) ob[j] = f2bf(o[j]);
    *(u16x8*)(Xbf + (size_t)row * 512 + lane * 8) = ob;
    float acc[8] = {0.f,0.f,0.f,0.f,0.f,0.f,0.f,0.f};
#pragma unroll
    for (int j = 0; j < 8; ++j)
#pragma unroll
      for (int e = 0; e < 8; ++e) acc[e] += o[j] * wg[j][e];
    float v4[4], v2[2], v1f;
#pragma unroll
    for (int i = 0; i < 4; ++i){
      float sel = (lane & 1) ? acc[i] : acc[i+4];
      float r = __shfl_xor(sel, 1, 64);
      v4[i] = ((lane & 1) ? acc[i+4] : acc[i]) + r;
    }
#pragma unroll
    for (int i = 0; i < 2; ++i){
      float sel = (lane & 2) ? v4[i] : v4[i+2];
      float r = __shfl_xor(sel, 2, 64);
      v2[i] = ((lane & 2) ? v4[i+2] : v4[i]) + r;
    }
    {
      float sel = (lane & 4) ? v2[0] : v2[1];
      float r = __shfl_xor(sel, 4, 64);
      v1f = ((lane & 4) ? v2[1] : v2[0]) + r;
    }
#pragma unroll
    for (int off = 8; off < 64; off <<= 1) v1f += __shfl_xor(v1f, off, 64);
    float lg[8];
#pragma unroll
    for (int e = 0; e < 8; ++e){
      int src = (lane & 56) | ((e >> 2) & 1) | (((e >> 1) & 1) << 1) | ((e & 1) << 2);
      lg[e] = __shfl(v1f, src, 64);
    }
    float mx = lg[0];
#pragma unroll
    for (int e = 1; e < 8; ++e) mx = fmaxf(mx, lg[e]);
    float pe[8], ps = 0.f;
#pragma unroll
    for (int e = 0; e < 8; ++e){ pe[e] = __expf(lg[e] - mx); ps += pe[e]; }
    float invp = 1.f / ps;
    int i1 = 0;
#pragma unroll
    for (int e = 1; e < 8; ++e) if (lg[e] > lg[i1]) i1 = e;
    int i2 = (i1 == 0) ? 1 : 0;
#pragma unroll
    for (int e = 0; e < 8; ++e) if (e != i1 && lg[e] > lg[i2]) i2 = e;
    float wA = 1.f / (1.f + __expf(lg[i2] - lg[i1]));
    if (lane == 0){
#pragma unroll
      for (int e = 0; e < 8; ++e) atomicAdd(&s_probs[e], pe[e] * invp);
      int r0 = atomicAdd(&s_cnt[i1], 1);
      int r1 = atomicAdd(&s_cnt[i2], 1);
      s_pk[tloc] = i1 | (r0 << 3) | (i2 << 8) | (r1 << 16);
      s_w[tloc] = wA;
    }
  }
  __syncthreads();
  if (tid < 8){
    BlockCnt[blockIdx.x * 8 + tid] = s_cnt[tid];
    BlockProbs[blockIdx.x * 8 + tid] = s_probs[tid];
  }
  if (tid < 16){
    int t = blockIdx.x * 16 + tid;
    PK[2*t]   = s_pk[tid];
    PK[2*t+1] = __builtin_bit_cast(int, s_w[tid]);
  }
}

// ------------- K2: all-expert parallel scan + parallel tile table + lb loss -------------
__global__ __launch_bounds__(256) void scan_k(
    const int* __restrict__ BlockCnt, const float* __restrict__ BlockProbs,
    int* __restrict__ BlockBase, int* __restrict__ CNT, int* __restrict__ nTiles,
    int* __restrict__ tileE, int* __restrict__ tileR0, int* __restrict__ rowBase,
    float* __restrict__ lbOut)
{
  __shared__ int sS[8][256];
  __shared__ float sF[8][256];
  __shared__ int sTileBase[9];
  const int tid = threadIdx.x;
  int local[8][8];
  int sum[8] = {0,0,0,0,0,0,0,0};
  float fsum[8] = {0.f,0.f,0.f,0.f,0.f,0.f,0.f,0.f};
#pragma unroll
  for (int jb = 0; jb < 8; ++jb){
    int blk = tid * 8 + jb;
#pragma unroll
    for (int e = 0; e < 8; ++e){
      int c = BlockCnt[blk*8 + e];
      local[jb][e] = c;
      sum[e] += c;
      fsum[e] += BlockProbs[blk*8 + e];
    }
  }
#pragma unroll
  for (int e = 0; e < 8; ++e){ sS[e][tid] = sum[e]; sF[e][tid] = fsum[e]; }
  __syncthreads();
  for (int off = 1; off < 256; off <<= 1){
    int add[8];
#pragma unroll
    for (int e = 0; e < 8; ++e) add[e] = (tid >= off) ? sS[e][tid - off] : 0;
    __syncthreads();
#pragma unroll
    for (int e = 0; e < 8; ++e) sS[e][tid] += add[e];
    __syncthreads();
  }
  for (int off = 128; off > 0; off >>= 1){
    if (tid < off)
#pragma unroll
      for (int e = 0; e < 8; ++e) sF[e][tid] += sF[e][tid + off];
    __syncthreads();
  }
  int base[8];
#pragma unroll
  for (int e = 0; e < 8; ++e) base[e] = (tid == 0) ? 0 : sS[e][tid-1];
#pragma unroll
  for (int jb = 0; jb < 8; ++jb){
    int blk = tid * 8 + jb;
#pragma unroll
    for (int e = 0; e < 8; ++e){ BlockBase[blk*8 + e] = base[e]; base[e] += local[jb][e]; }
  }
  if (tid == 0){
    int t = 0;
    float acc = 0.f;
    for (int e = 0; e < 8; ++e){
      int c = sS[e][255]; c = c < 0 ? 0 : (c > B_TOK ? B_TOK : c);
      CNT[e] = c;
      sTileBase[e] = t;
      rowBase[e] = t * 128;
      t += (c + 127) >> 7;
      acc += ((float)c / (float)(B_TOK * 2)) * (sF[e][0] / (float)B_TOK);
    }
    sTileBase[8] = t;
    nTiles[0] = t;
    lbOut[0] = 8.f * acc;
  }
  __syncthreads();
  const int ntot = sTileBase[8];
  for (int i = tid; i < MAXT; i += 256){
    int e = 0;
#pragma unroll
    for (int k = 1; k <= 8; ++k) if (i >= sTileBase[k]) e = k;
    if (i < ntot){ tileE[i] = e; tileR0[i] = (i - sTileBase[e]) * 128; }
    else { tileE[i] = 0; tileR0[i] = 0; }
  }
}

// ------------- K3: place tokens into routing lists (streaming, no atomics) -------------
__global__ __launch_bounds__(256) void place_k(
    const int* __restrict__ PK, const int* __restrict__ BlockBase,
    int* __restrict__ rowlist, int* __restrict__ TS, float* __restrict__ TW)
{
  const int t = blockIdx.x * 256 + threadIdx.x;
  int pk = PK[2*t];
  float w0 = __builtin_bit_cast(float, PK[2*t+1]);
  int e0 = pk & 7, r0 = (pk >> 3) & 31;
  int e1 = (pk >> 8) & 7, r1 = (pk >> 16) & 31;
  int blk = t >> 4;
  int p0 = BlockBase[blk*8 + e0] + r0;
  int p1 = BlockBase[blk*8 + e1] + r1;
  rowlist[(size_t)e0 * B_TOK + p0] = t;
  rowlist[(size_t)e1 * B_TOK + p1] = t;
  TS[2*t]   = (e0 << 15) | p0;  TW[2*t]   = w0;
  TS[2*t+1] = (e1 << 15) | p1;  TW[2*t+1] = 1.f - w0;
}

// ------------- final combine -------------
__global__ __launch_bounds__(256) void combine_k(
    const unsigned short* __restrict__ Xbf, const unsigned short* __restrict__ H3F,
    const int* __restrict__ TS, const float* __restrict__ TW,
    const int* __restrict__ rowBase, const float* __restrict__ ge,
    const float* __restrict__ be, float* __restrict__ out)
{
  const int tok = blockIdx.x * 4 + (threadIdx.x >> 6);
  const int lane = threadIdx.x & 63;
  u16x8 xb = *(const u16x8*)(Xbf + (size_t)tok * 512 + lane * 8);
  float x[8];
#pragma unroll
  for (int j = 0; j < 8; ++j) x[j] = bf2f(xb[j]);
  float o[8] = {0.f,0.f,0.f,0.f,0.f,0.f,0.f,0.f};
#pragma unroll
  for (int kslot = 0; kslot < 2; ++kslot){
    int sl = TS[tok*2 + kslot];
    float wgt = TW[tok*2 + kslot];
    int e = sl >> 15, p = sl & 32767;
    size_t hrow = (size_t)(rowBase[e] + p);
    u16x8 hb = *(const u16x8*)(H3F + hrow * 512 + lane * 8);
    float s[8];
#pragma unroll
    for (int j = 0; j < 8; ++j) s[j] = x[j] + bf2f(hb[j]);
    float sm = 0.f;
#pragma unroll
    for (int j = 0; j < 8; ++j) sm += s[j];
    sm = wredsum(sm);
    float mu = sm * (1.f / 512.f);
    float q = 0.f;
#pragma unroll
    for (int j = 0; j < 8; ++j){ float d = s[j] - mu; q += d * d; }
    q = wredsum(q);
    float inv = 1.f / sqrtf(q * (1.f / 512.f) + 1e-5f);
    const float4* gp = (const float4*)(ge + (size_t)e * 512 + lane * 8);
    const float4* bp = (const float4*)(be + (size_t)e * 512 + lane * 8);
    float4 g0 = gp[0], g1 = gp[1], c0 = bp[0], c1 = bp[1];
    float gg[8] = {g0.x,g0.y,g0.z,g0.w,g1.x,g1.y,g1.z,g1.w};
    float bb[8] = {c0.x,c0.y,c0.z,c0.w,c1.x,c1.y,c1.z,c1.w};
#pragma unroll
    for (int j = 0; j < 8; ++j)
      o[j] += wgt * ((s[j]-mu)*inv*gg[j] + bb[j]);
  }
  float* op = out + (size_t)tok * 512 + lane * 8;
  *(float4*)op       = make_float4(o[0], o[1], o[2], o[3]);
  *(float4*)(op + 4) = make_float4(o[4], o[5], o[6], o[7]);
}

extern "C" void kernel_launch(void* const* d_in, const int* in_sizes, int n_in,
                              void* d_out, int out_size, void* d_ws, size_t ws_size,
                              hipStream_t stream)
{
  (void)in_sizes; (void)n_in; (void)out_size;
  const float* vis   = (const float*)d_in[0];
  const float* lang  = (const float*)d_in[1];
  const float* state = (const float*)d_in[2];
  const float* Wf    = (const float*)d_in[3];
  const float* bf    = (const float*)d_in[4];
  const float* gf    = (const float*)d_in[5];
  const float* betaf = (const float*)d_in[6];
  const float* Wg    = (const float*)d_in[7];
  const float* W1    = (const float*)d_in[8];
  const float* b1    = (const float*)d_in[9];
  const float* W2    = (const float*)d_in[10];
  const float* b2    = (const float*)d_in[11];
  const float* W3    = (const float*)d_in[12];
  const float* b3    = (const float*)d_in[13];
  const float* ge    = (const float*)d_in[14];
  const float* be    = (const float*)d_in[15];

  char* ws = (char*)d_ws;
  size_t off = 0;
  auto alloc = [&](size_t n){ size_t o = off; off += (n + 255) & ~(size_t)255; return o; };

  unsigned short* WFH  = (unsigned short*)(ws + alloc((size_t)512*512*2));
  unsigned short* WFL  = (unsigned short*)(ws + alloc((size_t)512*512*2));
  unsigned short* W1T  = (unsigned short*)(ws + alloc((size_t)8*1024*512*2));
  unsigned short* W2T  = (unsigned short*)(ws + alloc((size_t)8*512*1024*2));
  unsigned short* W3T  = (unsigned short*)(ws + alloc((size_t)8*512*512*2));
  unsigned short* XBF  = (unsigned short*)(ws + alloc((size_t)B_TOK*512*2));
  int*            RLIST= (int*)(ws + alloc((size_t)8*B_TOK*4));
  int*            TS   = (int*)(ws + alloc((size_t)B_TOK*2*4));
  float*          TW   = (float*)(ws + alloc((size_t)B_TOK*2*4));
  int*            PK   = (int*)(ws + alloc((size_t)B_TOK*2*4));
  int*            BCNT = (int*)(ws + alloc((size_t)NBLK*8*4));
  float*          BPROB= (float*)(ws + alloc((size_t)NBLK*8*4));
  int*            BBASE= (int*)(ws + alloc((size_t)NBLK*8*4));
  int*            CNT  = (int*)(ws + alloc(64));
  int*            NT_  = (int*)(ws + alloc(64));
  int*            RB   = (int*)(ws + alloc(64));
  int*            TE   = (int*)(ws + alloc(MAXT*4));
  int*            TR   = (int*)(ws + alloc(MAXT*4));
  unsigned short* H3F  = (unsigned short*)(ws + alloc((size_t)MAXT*128*512*2));  // 68 MB persistent

  const size_t perTile = (size_t)128*1024*2 + (size_t)128*512*2;
  size_t remain = (ws_size > off) ? (ws_size - off) : 0;
  int tch, nch;
  size_t need2 = (size_t)260 * perTile, need4 = (size_t)B_TOK*512*4;
  if (remain >= need2 && need2 >= need4){ tch = 260; nch = 2; }
  else { tch = 130; nch = 4; }
  size_t regB = alloc(need2 > need4 ? (nch == 2 ? need2 : need4) : need4);
  float*          XPRE = (float*)(ws + regB);
  unsigned short* H1   = (unsigned short*)(ws + regB);
  unsigned short* H2   = H1 + (size_t)tch*128*1024;
  const int tpg = (tch + 7) / 8;

  transpose_split_f16_k<<<dim3(16,16,1), dim3(32,8), 0, stream>>>(Wf, WFH, WFL, 512, 512);
  transpose_cast_bf16_k<<<dim3(32,16,8), dim3(32,8), 0, stream>>>(W1, W1T, 512, 1024);
  transpose_cast_bf16_k<<<dim3(16,32,8), dim3(32,8), 0, stream>>>(W2, W2T, 1024, 512);
  transpose_cast_bf16_k<<<dim3(16,16,8), dim3(32,8), 0, stream>>>(W3, W3T, 512, 512);
  gemm_fusion_f16split<<<dim3(256,4), 256, 0, stream>>>(vis, lang, state, WFH, WFL, bf, XPRE);
  ln_gelu_gate_k<<<NBLK, 256, 0, stream>>>(XPRE, gf, betaf, Wg, XBF, PK, BCNT, BPROB);
  scan_k<<<1, 256, 0, stream>>>(BCNT, BPROB, BBASE, CNT, NT_, TE, TR, RB,
                                ((float*)d_out) + (size_t)B_TOK*512);
  place_k<<<B_TOK/256, 256, 0, stream>>>(PK, BBASE, RLIST, TS, TW);

  for (int c = 0; c < nch; ++c){
    int cb = c * tch;
    egemm_k<512, 1024, 8, true,  true,  false><<<dim3(8*tpg*8), 256, 0, stream>>>(
        XBF, RLIST, CNT, NT_, TE, TR, cb, tch, tpg, W1T, b1, H1);
    egemm_k<1024, 512, 4, false, true,  false><<<dim3(8*tpg*4), 256, 0, stream>>>(
        H1,  RLIST, CNT, NT_, TE, TR, cb, tch, tpg, W2T, b2, H2);
    egemm_k<512,  512, 4, false, false, true ><<<dim3(8*tpg*4), 256, 0, stream>>>(
        H2,  RLIST, CNT, NT_, TE, TR, cb, tch, tpg, W3T, b3, H3F);
  }
  combine_k<<<B_TOK/4, 256, 0, stream>>>(XBF, H3F, TS, TW, RB, ge, be, (float*)d_out);
}